// Round 13
// baseline (127.211 us; speedup 1.0000x reference)
//
#include <hip/hip_runtime.h>
#include <hip/hip_fp16.h>

// Problem constants (from reference setup_inputs)
constexpr int Bsz   = 1024;     // batch
constexpr int F0    = 20000;    // input features
constexpr int NOUT0 = 5000, NOUT1 = 1000, NOUT2 = 256;
constexpr int NE0   = 100000, NE1 = 50000, NE2 = 10000;
constexpr int CNT_N  = NOUT0 + NOUT1 + NOUT2;   // 6256
constexpr int OFFS_N = CNT_N + 3;               // 6259
constexpr int CSR_N  = NE0 + NE1 + NE2;         // 160000
constexpr int MAXIDX = 512;                      // max edges staged per dst
constexpr int NTILE_F = (F0 + 63) / 64;          // 313
constexpr int NTILE   = NTILE_F * (Bsz / 64);    // 5008 transpose tiles
constexpr int SCB     = (CSR_N + 255) / 256;     // 625 scatter blocks
constexpr int NSLICE  = 8;                       // column slices == XCD count
constexpr int SLW     = Bsz / NSLICE;            // 128 cols per slice (l1/l2)

union H4 { uint2 u; __half2 h[2]; };

// ---------------------------------------------------------------------------
// count dst in-degrees (wide, global atomics).
__global__ __launch_bounds__(256) void count_edges(
    const int* __restrict__ dst0, const int* __restrict__ dst1,
    const int* __restrict__ dst2, int* __restrict__ cnt)
{
    const int i = blockIdx.x * 256 + threadIdx.x;
    if (i < NE0)                 atomicAdd(&cnt[dst0[i]], 1);
    else if (i < NE0 + NE1)      atomicAdd(&cnt[NOUT0 + dst1[i - NE0]], 1);
    else if (i < CSR_N)          atomicAdd(&cnt[NOUT0 + NOUT1 + dst2[i - NE0 - NE1]], 1);
}

// ---------------------------------------------------------------------------
// scan counts -> offs + cursor. 3 blocks (one per layer).
__global__ __launch_bounds__(1024) void scan_offs(
    const int* __restrict__ cnt, int* __restrict__ offs, int* __restrict__ cursor)
{
    const int L = blockIdx.x;
    const int t = threadIdx.x;
    const int n  = (L == 0) ? NOUT0 : (L == 1) ? NOUT1 : NOUT2;
    const int cb = (L == 0) ? 0 : (L == 1) ? NOUT0 : NOUT0 + NOUT1;
    const int ob = (L == 0) ? 0 : (L == 1) ? NOUT0 + 1 : NOUT0 + NOUT1 + 2;
    const int* c = cnt + cb;
    int* ofs = offs + ob;
    int* cur = cursor + cb;

    __shared__ int sc[1024];
    constexpr int CH = 5;                 // 1024*5 = 5120 >= 5000
    const int base = t * CH;
    int vals[CH];
    int local = 0;
#pragma unroll
    for (int k = 0; k < CH; ++k) {
        const int i = base + k;
        const int v = (i < n) ? c[i] : 0;
        vals[k] = v; local += v;
    }
    sc[t] = local;
    __syncthreads();
    for (int d = 1; d < 1024; d <<= 1) {
        const int v = (t >= d) ? sc[t - d] : 0;
        __syncthreads();
        sc[t] += v;
        __syncthreads();
    }
    int excl = sc[t] - local;
#pragma unroll
    for (int k = 0; k < CH; ++k) {
        const int i = base + k;
        if (i < n) { ofs[i] = excl; cur[i] = excl; }
        excl += vals[k];
    }
    if (t == 1023) ofs[n] = sc[1023];
}

// ---------------------------------------------------------------------------
// transpose+scale (blocks < NTILE) || edge scatter (the rest).
__global__ __launch_bounds__(256) void transpose_scatter(
    const float* __restrict__ data, const float* __restrict__ p0,
    __half* __restrict__ dataT,
    const int* __restrict__ src0, const int* __restrict__ dst0,
    const int* __restrict__ src1, const int* __restrict__ dst1,
    const int* __restrict__ src2, const int* __restrict__ dst2,
    int* __restrict__ cursor, int* __restrict__ csr)
{
    const int t = threadIdx.x;
    const int bid = blockIdx.x;
    if (bid < NTILE) {
        __shared__ float tile[64][65];
        const int c0 = (bid % NTILE_F) * 64;   // F0 dim
        const int r0 = (bid / NTILE_F) * 64;   // B dim
        const int f4 = t & 15, rr = t >> 4;
        const int col = c0 + f4 * 4;
        if (col < F0) {                        // F0 % 4 == 0: exact guard
#pragma unroll
            for (int p = 0; p < 4; ++p) {
                const int br = rr + p * 16;
                const float4 v = *(const float4*)&data[(size_t)(r0 + br) * F0 + col];
                tile[br][f4 * 4 + 0] = v.x; tile[br][f4 * 4 + 1] = v.y;
                tile[br][f4 * 4 + 2] = v.z; tile[br][f4 * 4 + 3] = v.w;
            }
        }
        __syncthreads();
        const int b4 = t & 15, fr = t >> 4;
#pragma unroll
        for (int p = 0; p < 4; ++p) {
            const int f = c0 + fr + p * 16;
            if (f < F0) {
                const float s = p0[f];
                H4 o;
                o.h[0] = __floats2half2_rn(tile[b4 * 4 + 0][fr + p * 16] * s,
                                           tile[b4 * 4 + 1][fr + p * 16] * s);
                o.h[1] = __floats2half2_rn(tile[b4 * 4 + 2][fr + p * 16] * s,
                                           tile[b4 * 4 + 3][fr + p * 16] * s);
                *(uint2*)&dataT[(size_t)f * Bsz + r0 + b4 * 4] = o.u;
            }
        }
    } else {
        const int i = (bid - NTILE) * 256 + t;
        if (i < NE0) {
            const int pos = atomicAdd(&cursor[dst0[i]], 1);
            csr[pos] = src0[i];
        } else if (i < NE0 + NE1) {
            const int k = i - NE0;
            const int pos = atomicAdd(&cursor[NOUT0 + dst1[k]], 1);
            csr[NE0 + pos] = src1[k];
        } else if (i < CSR_N) {
            const int k = i - NE0 - NE1;
            const int pos = atomicAdd(&cursor[NOUT0 + NOUT1 + dst2[k]], 1);
            csr[NE0 + NE1 + pos] = src2[k];
        }
    }
}

// ---------------------------------------------------------------------------
// Layer 0, narrow-slice form: HALF selects batch-column half (0: cols 0-511,
// 1: cols 512-1023). 8 slices of 64 cols -> per-XCD L2 working set
// 20000 x 64 x 2B = 2.56MB (fully resident in the 4MB XCD L2).
// Each wave processes TWO edges at once: lanes 0-31 edge e, lanes 32-63 edge
// e+1 (two 128B segments per load instruction); combined via shfl_xor(32).
template<int HALF>
__global__ __launch_bounds__(64) void layer0_slice(
    const __half* __restrict__ xT, const int* __restrict__ csr,
    const int* __restrict__ offs, const float* __restrict__ p1,
    __half* __restrict__ y0)
{
    __shared__ int sidx[MAXIDX];
    const int bid = blockIdx.x;
    const int slice = bid & (NSLICE - 1);
    const int j = bid >> 3;
    const int t = threadIdx.x;
    const int beg = offs[j], end = offs[j + 1];
    const int n = end - beg;
    const int np = n < MAXIDX ? n : MAXIDX;
    for (int i = t; i < np; i += 64) sidx[i] = csr[beg + i];
    __syncthreads();

    const int c  = HALF * 512 + slice * 64 + (t & 31) * 2;
    const int ep = t >> 5;               // which edge of the pair this lane owns
    float a0x = 0.f, a0y = 0.f, a1x = 0.f, a1y = 0.f;
    float a2x = 0.f, a2y = 0.f, a3x = 0.f, a3y = 0.f;
    int e = 0;
    for (; e + 8 <= np; e += 8) {
        const int s0 = sidx[e + 0 + ep];
        const int s1 = sidx[e + 2 + ep];
        const int s2 = sidx[e + 4 + ep];
        const int s3 = sidx[e + 6 + ep];
        const float2 f0 = __half22float2(*(const __half2*)&xT[(size_t)s0 * Bsz + c]);
        const float2 f1 = __half22float2(*(const __half2*)&xT[(size_t)s1 * Bsz + c]);
        const float2 f2 = __half22float2(*(const __half2*)&xT[(size_t)s2 * Bsz + c]);
        const float2 f3 = __half22float2(*(const __half2*)&xT[(size_t)s3 * Bsz + c]);
        a0x += f0.x; a0y += f0.y; a1x += f1.x; a1y += f1.y;
        a2x += f2.x; a2y += f2.y; a3x += f3.x; a3y += f3.y;
    }
    for (; e < np; e += 2) {
        const int idx = e + ep;
        const float m = (idx < np) ? 1.f : 0.f;
        const int s = sidx[(idx < np) ? idx : 0];
        const float2 f = __half22float2(*(const __half2*)&xT[(size_t)s * Bsz + c]);
        a0x += m * f.x; a0y += m * f.y;
    }
    for (int ee = MAXIDX; ee < n; ++ee) {   // overflow fallback (never in practice)
        const float m = (ep == 0) ? 1.f : 0.f;
        const float2 f = __half22float2(*(const __half2*)&xT[(size_t)csr[beg + ee] * Bsz + c]);
        a0x += m * f.x; a0y += m * f.y;
    }
    float ax = a0x + a1x + a2x + a3x;
    float ay = a0y + a1y + a2y + a3y;
    ax += __shfl_xor(ax, 32);
    ay += __shfl_xor(ay, 32);

    if (t < 32) {
        const float inv = 1.0f / fmaxf((float)n, 1.0f);
        const float sc = p1[j] * inv;
        *(__half2*)&y0[(size_t)j * Bsz + c] =
            __floats2half2_rn(fmaxf(ax, 0.f) * sc, fmaxf(ay, 0.f) * sc);
    }
}

// ---------------------------------------------------------------------------
// Layers 1,2: XCD-sliced gather (128-col slices, already L2-resident).
template<int LAYER>
__global__ __launch_bounds__(64) void layer_slice(
    const __half* __restrict__ xT, const int* __restrict__ csr,
    const int* __restrict__ offs, const float* __restrict__ pnext,
    __half* __restrict__ yT)
{
    __shared__ int sidx[MAXIDX];
    const int bid = blockIdx.x;
    const int slice = bid & (NSLICE - 1);
    const int j = bid >> 3;
    const int t = threadIdx.x;
    const int beg = offs[j], end = offs[j + 1];
    const int n = end - beg;
    const int np = n < MAXIDX ? n : MAXIDX;
    for (int i = t; i < np; i += 64) sidx[i] = csr[beg + i];
    __syncthreads();

    const int c = slice * SLW + t * 2;
    float a0x = 0.f, a0y = 0.f, a1x = 0.f, a1y = 0.f;
    float a2x = 0.f, a2y = 0.f, a3x = 0.f, a3y = 0.f;
    int e = 0;
    for (; e + 4 <= np; e += 4) {
        const __half2 v0 = *(const __half2*)&xT[(size_t)sidx[e + 0] * Bsz + c];
        const __half2 v1 = *(const __half2*)&xT[(size_t)sidx[e + 1] * Bsz + c];
        const __half2 v2 = *(const __half2*)&xT[(size_t)sidx[e + 2] * Bsz + c];
        const __half2 v3 = *(const __half2*)&xT[(size_t)sidx[e + 3] * Bsz + c];
        const float2 f0 = __half22float2(v0);
        const float2 f1 = __half22float2(v1);
        const float2 f2 = __half22float2(v2);
        const float2 f3 = __half22float2(v3);
        a0x += f0.x; a0y += f0.y; a1x += f1.x; a1y += f1.y;
        a2x += f2.x; a2y += f2.y; a3x += f3.x; a3y += f3.y;
    }
    for (; e < np; ++e) {
        const float2 f = __half22float2(*(const __half2*)&xT[(size_t)sidx[e] * Bsz + c]);
        a0x += f.x; a0y += f.y;
    }
    for (int ee = MAXIDX; ee < n; ++ee) {   // overflow fallback (never in practice)
        const float2 f = __half22float2(*(const __half2*)&xT[(size_t)csr[beg + ee] * Bsz + c]);
        a0x += f.x; a0y += f.y;
    }
    const float ax = a0x + a1x + a2x + a3x;
    const float ay = a0y + a1y + a2y + a3y;

    const float inv = 1.0f / fmaxf((float)n, 1.0f);
    const float sc = (pnext ? pnext[j] : 1.0f) * inv;
    const __half2 o = __floats2half2_rn(fmaxf(ax, 0.f) * sc, fmaxf(ay, 0.f) * sc);
    *(__half2*)&yT[(size_t)j * Bsz + c] = o;
}

// ---------------------------------------------------------------------------
// head GEMM. out (B,10) = y2 (B,256) @ W.T + b, y2 transposed fp16.
__global__ __launch_bounds__(256) void head_gemm(
    const __half* __restrict__ y2T, const float* __restrict__ W,
    const float* __restrict__ bias, float* __restrict__ out)
{
    __shared__ float ws[10 * 256];
    __shared__ float bs[10];
    const int t = threadIdx.x;
    for (int i = t; i < 10 * 256; i += 256) ws[i] = W[i];
    if (t < 10) bs[t] = bias[t];
    __syncthreads();

    const int b = blockIdx.x * 256 + t;
    float acc[10];
#pragma unroll
    for (int o = 0; o < 10; ++o) acc[o] = bs[o];
    for (int k = 0; k < 256; ++k) {
        const float v = __half2float(y2T[(size_t)k * Bsz + b]);
#pragma unroll
        for (int o = 0; o < 10; ++o) acc[o] += v * ws[o * 256 + k];
    }
#pragma unroll
    for (int o = 0; o < 10; ++o) out[(size_t)b * 10 + o] = acc[o];
}

// ---------------------------------------------------------------------------
extern "C" void kernel_launch(void* const* d_in, const int* in_sizes, int n_in,
                              void* d_out, int out_size, void* d_ws, size_t ws_size,
                              hipStream_t stream)
{
    const float* data = (const float*)d_in[0];
    const float* p0   = (const float*)d_in[1];
    const float* p1   = (const float*)d_in[2];
    const float* p2   = (const float*)d_in[3];
    const float* W    = (const float*)d_in[4];
    const float* bias = (const float*)d_in[5];
    const int* src0 = (const int*)d_in[6];
    const int* dst0 = (const int*)d_in[7];
    const int* src1 = (const int*)d_in[8];
    const int* dst1 = (const int*)d_in[9];
    const int* src2 = (const int*)d_in[10];
    const int* dst2 = (const int*)d_in[11];

    char* ws = (char*)d_ws;
    auto align = [](size_t x) { return (x + 255) & ~size_t(255); };
    size_t o = 0;
    __half* dataT = (__half*)(ws + o); o = align(o + (size_t)F0 * Bsz * 2);
    __half* y0    = (__half*)(ws + o); o = align(o + (size_t)NOUT0 * Bsz * 2);
    __half* y1    = (__half*)(ws + o); o = align(o + (size_t)NOUT1 * Bsz * 2);
    __half* y2    = (__half*)(ws + o); o = align(o + (size_t)NOUT2 * Bsz * 2);
    int* cnt      = (int*)(ws + o);    o = align(o + (size_t)CNT_N * 4);
    int* offs     = (int*)(ws + o);    o = align(o + (size_t)OFFS_N * 4);
    int* cursor   = (int*)(ws + o);    o = align(o + (size_t)CNT_N * 4);
    int* csr      = (int*)(ws + o);    o = align(o + (size_t)CSR_N * 4);

    hipMemsetAsync(cnt, 0, (size_t)CNT_N * 4, stream);
    count_edges<<<SCB, 256, 0, stream>>>(dst0, dst1, dst2, cnt);
    scan_offs<<<3, 1024, 0, stream>>>(cnt, offs, cursor);
    transpose_scatter<<<NTILE + SCB, 256, 0, stream>>>(
        data, p0, dataT, src0, dst0, src1, dst1, src2, dst2, cursor, csr);
    layer0_slice<0><<<NOUT0 * NSLICE, 64, 0, stream>>>(dataT, csr, offs, p1, y0);
    layer0_slice<1><<<NOUT0 * NSLICE, 64, 0, stream>>>(dataT, csr, offs, p1, y0);
    layer_slice<1><<<NOUT1 * NSLICE, 64, 0, stream>>>(y0, csr + NE0, offs + NOUT0 + 1, p2, y1);
    layer_slice<2><<<NOUT2 * NSLICE, 64, 0, stream>>>(y1, csr + NE0 + NE1,
                                                      offs + NOUT0 + NOUT1 + 2, nullptr, y2);
    head_gemm<<<Bsz / 256, 256, 0, stream>>>(y2, W, bias, (float*)d_out);
}

// Round 14
// 120.778 us; speedup vs baseline: 1.0533x; 1.0533x over previous
//
#include <hip/hip_runtime.h>
#include <hip/hip_fp16.h>

// Problem constants (from reference setup_inputs)
constexpr int Bsz   = 1024;     // batch
constexpr int F0    = 20000;    // input features
constexpr int NOUT0 = 5000, NOUT1 = 1000, NOUT2 = 256;
constexpr int NE0   = 100000, NE1 = 50000, NE2 = 10000;
constexpr int CNT_N  = NOUT0 + NOUT1 + NOUT2;   // 6256
constexpr int OFFS_N = CNT_N + 3;               // 6259
constexpr int CSR_N  = NE0 + NE1 + NE2;         // 160000
constexpr int NTILE_F = (F0 + 63) / 64;          // 313
constexpr int NTILE   = NTILE_F * (Bsz / 64);    // 5008 transpose tiles
constexpr int SCB     = (CSR_N + 255) / 256;     // 625 scatter blocks
constexpr int NSLICE  = 8;                       // column slices == XCD count
constexpr int SLW     = Bsz / NSLICE;            // 128 cols per slice
constexpr int MAXW    = 128;                     // max edges staged per dst (max deg ~85)

union H4 { uint2 u; __half2 h[2]; };
union H8 { uint4 u4; __half2 h[4]; };

// ---------------------------------------------------------------------------
// count dst in-degrees (wide, global atomics).
__global__ __launch_bounds__(256) void count_edges(
    const int* __restrict__ dst0, const int* __restrict__ dst1,
    const int* __restrict__ dst2, int* __restrict__ cnt)
{
    const int i = blockIdx.x * 256 + threadIdx.x;
    if (i < NE0)                 atomicAdd(&cnt[dst0[i]], 1);
    else if (i < NE0 + NE1)      atomicAdd(&cnt[NOUT0 + dst1[i - NE0]], 1);
    else if (i < CSR_N)          atomicAdd(&cnt[NOUT0 + NOUT1 + dst2[i - NE0 - NE1]], 1);
}

// ---------------------------------------------------------------------------
// scan counts -> offs + cursor. 3 blocks (one per layer).
__global__ __launch_bounds__(1024) void scan_offs(
    const int* __restrict__ cnt, int* __restrict__ offs, int* __restrict__ cursor)
{
    const int L = blockIdx.x;
    const int t = threadIdx.x;
    const int n  = (L == 0) ? NOUT0 : (L == 1) ? NOUT1 : NOUT2;
    const int cb = (L == 0) ? 0 : (L == 1) ? NOUT0 : NOUT0 + NOUT1;
    const int ob = (L == 0) ? 0 : (L == 1) ? NOUT0 + 1 : NOUT0 + NOUT1 + 2;
    const int* c = cnt + cb;
    int* ofs = offs + ob;
    int* cur = cursor + cb;

    __shared__ int sc[1024];
    constexpr int CH = 5;                 // 1024*5 = 5120 >= 5000
    const int base = t * CH;
    int vals[CH];
    int local = 0;
#pragma unroll
    for (int k = 0; k < CH; ++k) {
        const int i = base + k;
        const int v = (i < n) ? c[i] : 0;
        vals[k] = v; local += v;
    }
    sc[t] = local;
    __syncthreads();
    for (int d = 1; d < 1024; d <<= 1) {
        const int v = (t >= d) ? sc[t - d] : 0;
        __syncthreads();
        sc[t] += v;
        __syncthreads();
    }
    int excl = sc[t] - local;
#pragma unroll
    for (int k = 0; k < CH; ++k) {
        const int i = base + k;
        if (i < n) { ofs[i] = excl; cur[i] = excl; }
        excl += vals[k];
    }
    if (t == 1023) ofs[n] = sc[1023];
}

// ---------------------------------------------------------------------------
// transpose+scale (blocks < NTILE) || edge scatter (the rest).
// Store side now uint4 (8 halves / 16B per lane) — half the store instructions.
__global__ __launch_bounds__(256) void transpose_scatter(
    const float* __restrict__ data, const float* __restrict__ p0,
    __half* __restrict__ dataT,
    const int* __restrict__ src0, const int* __restrict__ dst0,
    const int* __restrict__ src1, const int* __restrict__ dst1,
    const int* __restrict__ src2, const int* __restrict__ dst2,
    int* __restrict__ cursor, int* __restrict__ csr)
{
    const int t = threadIdx.x;
    const int bid = blockIdx.x;
    if (bid < NTILE) {
        __shared__ float tile[64][65];
        const int c0 = (bid % NTILE_F) * 64;   // F0 dim
        const int r0 = (bid / NTILE_F) * 64;   // B dim
        const int f4 = t & 15, rr = t >> 4;
        const int col = c0 + f4 * 4;
        if (col < F0) {                        // F0 % 4 == 0: exact guard
#pragma unroll
            for (int p = 0; p < 4; ++p) {
                const int br = rr + p * 16;
                const float4 v = *(const float4*)&data[(size_t)(r0 + br) * F0 + col];
                tile[br][f4 * 4 + 0] = v.x; tile[br][f4 * 4 + 1] = v.y;
                tile[br][f4 * 4 + 2] = v.z; tile[br][f4 * 4 + 3] = v.w;
            }
        }
        __syncthreads();
        const int b8 = t & 7, fr = t >> 3;     // fr 0..31; b8: 8 cols-of-8
#pragma unroll
        for (int p = 0; p < 2; ++p) {
            const int f = c0 + fr + p * 32;
            if (f < F0) {
                const float s = p0[f];
                H8 o;
#pragma unroll
                for (int k = 0; k < 4; ++k)
                    o.h[k] = __floats2half2_rn(tile[b8 * 8 + 2 * k + 0][fr + p * 32] * s,
                                               tile[b8 * 8 + 2 * k + 1][fr + p * 32] * s);
                *(uint4*)&dataT[(size_t)f * Bsz + r0 + b8 * 8] = o.u4;
            }
        }
    } else {
        const int i = (bid - NTILE) * 256 + t;
        if (i < NE0) {
            const int pos = atomicAdd(&cursor[dst0[i]], 1);
            csr[pos] = src0[i];
        } else if (i < NE0 + NE1) {
            const int k = i - NE0;
            const int pos = atomicAdd(&cursor[NOUT0 + dst1[k]], 1);
            csr[NE0 + pos] = src1[k];
        } else if (i < CSR_N) {
            const int k = i - NE0 - NE1;
            const int pos = atomicAdd(&cursor[NOUT0 + NOUT1 + dst2[k]], 1);
            csr[NE0 + NE1 + pos] = src2[k];
        }
    }
}

// ---------------------------------------------------------------------------
// Gather layers: 256-thread blocks, 4 dsts per block (one per wave).
// Block = (jgroup, slice); slice = bid & 7 (XCD round-robin), wave w handles
// dst j = jgroup*4 + w over cols [slice*128, slice*128+128) (half2 per lane).
// All of NOUT0/1/2 are divisible by 4, so no tail guard needed.
template<int LAYER>
__global__ __launch_bounds__(256) void layer_slice4(
    const __half* __restrict__ xT, const int* __restrict__ csr,
    const int* __restrict__ offs, const float* __restrict__ pnext,
    __half* __restrict__ yT)
{
    __shared__ int sidx[4][MAXW];
    const int bid = blockIdx.x;
    const int slice = bid & (NSLICE - 1);
    const int jg = bid >> 3;
    const int w = threadIdx.x >> 6;
    const int lane = threadIdx.x & 63;
    const int j = jg * 4 + w;
    const int beg = offs[j], end = offs[j + 1];
    const int n = end - beg;
    const int np = n < MAXW ? n : MAXW;
    for (int i = lane; i < np; i += 64) sidx[w][i] = csr[beg + i];
    __syncthreads();

    const int c = slice * SLW + lane * 2;
    float a0x = 0.f, a0y = 0.f, a1x = 0.f, a1y = 0.f;
    float a2x = 0.f, a2y = 0.f, a3x = 0.f, a3y = 0.f;
    int e = 0;
    for (; e + 4 <= np; e += 4) {
        const __half2 v0 = *(const __half2*)&xT[(size_t)sidx[w][e + 0] * Bsz + c];
        const __half2 v1 = *(const __half2*)&xT[(size_t)sidx[w][e + 1] * Bsz + c];
        const __half2 v2 = *(const __half2*)&xT[(size_t)sidx[w][e + 2] * Bsz + c];
        const __half2 v3 = *(const __half2*)&xT[(size_t)sidx[w][e + 3] * Bsz + c];
        const float2 f0 = __half22float2(v0);
        const float2 f1 = __half22float2(v1);
        const float2 f2 = __half22float2(v2);
        const float2 f3 = __half22float2(v3);
        a0x += f0.x; a0y += f0.y; a1x += f1.x; a1y += f1.y;
        a2x += f2.x; a2y += f2.y; a3x += f3.x; a3y += f3.y;
    }
    for (; e < np; ++e) {
        const float2 f = __half22float2(*(const __half2*)&xT[(size_t)sidx[w][e] * Bsz + c]);
        a0x += f.x; a0y += f.y;
    }
    for (int ee = MAXW; ee < n; ++ee) {   // overflow fallback (never in practice)
        const float2 f = __half22float2(*(const __half2*)&xT[(size_t)csr[beg + ee] * Bsz + c]);
        a0x += f.x; a0y += f.y;
    }
    const float ax = a0x + a1x + a2x + a3x;
    const float ay = a0y + a1y + a2y + a3y;

    const float inv = 1.0f / fmaxf((float)n, 1.0f);
    const float sc = (pnext ? pnext[j] : 1.0f) * inv;
    const __half2 o = __floats2half2_rn(fmaxf(ax, 0.f) * sc, fmaxf(ay, 0.f) * sc);
    *(__half2*)&yT[(size_t)j * Bsz + c] = o;
}

// ---------------------------------------------------------------------------
// head GEMM. out (B,10) = y2 (B,256) @ W.T + b, y2 transposed fp16.
__global__ __launch_bounds__(256) void head_gemm(
    const __half* __restrict__ y2T, const float* __restrict__ W,
    const float* __restrict__ bias, float* __restrict__ out)
{
    __shared__ float ws[10 * 256];
    __shared__ float bs[10];
    const int t = threadIdx.x;
    for (int i = t; i < 10 * 256; i += 256) ws[i] = W[i];
    if (t < 10) bs[t] = bias[t];
    __syncthreads();

    const int b = blockIdx.x * 256 + t;
    float acc[10];
#pragma unroll
    for (int o = 0; o < 10; ++o) acc[o] = bs[o];
    for (int k = 0; k < 256; ++k) {
        const float v = __half2float(y2T[(size_t)k * Bsz + b]);
#pragma unroll
        for (int o = 0; o < 10; ++o) acc[o] += v * ws[o * 256 + k];
    }
#pragma unroll
    for (int o = 0; o < 10; ++o) out[(size_t)b * 10 + o] = acc[o];
}

// ---------------------------------------------------------------------------
extern "C" void kernel_launch(void* const* d_in, const int* in_sizes, int n_in,
                              void* d_out, int out_size, void* d_ws, size_t ws_size,
                              hipStream_t stream)
{
    const float* data = (const float*)d_in[0];
    const float* p0   = (const float*)d_in[1];
    const float* p1   = (const float*)d_in[2];
    const float* p2   = (const float*)d_in[3];
    const float* W    = (const float*)d_in[4];
    const float* bias = (const float*)d_in[5];
    const int* src0 = (const int*)d_in[6];
    const int* dst0 = (const int*)d_in[7];
    const int* src1 = (const int*)d_in[8];
    const int* dst1 = (const int*)d_in[9];
    const int* src2 = (const int*)d_in[10];
    const int* dst2 = (const int*)d_in[11];

    char* ws = (char*)d_ws;
    auto align = [](size_t x) { return (x + 255) & ~size_t(255); };
    size_t o = 0;
    __half* dataT = (__half*)(ws + o); o = align(o + (size_t)F0 * Bsz * 2);
    __half* y0    = (__half*)(ws + o); o = align(o + (size_t)NOUT0 * Bsz * 2);
    __half* y1    = (__half*)(ws + o); o = align(o + (size_t)NOUT1 * Bsz * 2);
    __half* y2    = (__half*)(ws + o); o = align(o + (size_t)NOUT2 * Bsz * 2);
    int* cnt      = (int*)(ws + o);    o = align(o + (size_t)CNT_N * 4);
    int* offs     = (int*)(ws + o);    o = align(o + (size_t)OFFS_N * 4);
    int* cursor   = (int*)(ws + o);    o = align(o + (size_t)CNT_N * 4);
    int* csr      = (int*)(ws + o);    o = align(o + (size_t)CSR_N * 4);

    hipMemsetAsync(cnt, 0, (size_t)CNT_N * 4, stream);
    count_edges<<<SCB, 256, 0, stream>>>(dst0, dst1, dst2, cnt);
    scan_offs<<<3, 1024, 0, stream>>>(cnt, offs, cursor);
    transpose_scatter<<<NTILE + SCB, 256, 0, stream>>>(
        data, p0, dataT, src0, dst0, src1, dst1, src2, dst2, cursor, csr);
    layer_slice4<0><<<(NOUT0 / 4) * NSLICE, 256, 0, stream>>>(dataT, csr, offs, p1, y0);
    layer_slice4<1><<<(NOUT1 / 4) * NSLICE, 256, 0, stream>>>(y0, csr + NE0, offs + NOUT0 + 1, p2, y1);
    layer_slice4<2><<<(NOUT2 / 4) * NSLICE, 256, 0, stream>>>(y1, csr + NE0 + NE1,
                                                              offs + NOUT0 + NOUT1 + 2, nullptr, y2);
    head_gemm<<<Bsz / 256, 256, 0, stream>>>(y2, W, bias, (float*)d_out);
}

// Round 15
// 117.486 us; speedup vs baseline: 1.0828x; 1.0280x over previous
//
#include <hip/hip_runtime.h>
#include <hip/hip_fp16.h>

// Problem constants (from reference setup_inputs)
constexpr int Bsz   = 1024;     // batch
constexpr int F0    = 20000;    // input features
constexpr int NOUT0 = 5000, NOUT1 = 1000, NOUT2 = 256;
constexpr int NE0   = 100000, NE1 = 50000, NE2 = 10000;
constexpr int CNT_N  = NOUT0 + NOUT1 + NOUT2;   // 6256
constexpr int OFFS_N = CNT_N + 3;               // 6259
constexpr int CSR_N  = NE0 + NE1 + NE2;         // 160000
constexpr int MAXIDX = 512;                      // max edges staged per dst
constexpr int NTILE_F = (F0 + 63) / 64;          // 313
constexpr int NTILE   = NTILE_F * (Bsz / 64);    // 5008 transpose tiles
constexpr int SCB     = (CSR_N + 255) / 256;     // 625 scatter blocks
constexpr int NSLICE  = 8;                       // column slices == XCD count
constexpr int SLW     = Bsz / NSLICE;            // 128 cols per slice

union H4 { uint2 u; __half2 h[2]; };
union H8 { uint4 u4; __half2 h[4]; };

// ---------------------------------------------------------------------------
// count dst in-degrees (wide, global atomics).
__global__ __launch_bounds__(256) void count_edges(
    const int* __restrict__ dst0, const int* __restrict__ dst1,
    const int* __restrict__ dst2, int* __restrict__ cnt)
{
    const int i = blockIdx.x * 256 + threadIdx.x;
    if (i < NE0)                 atomicAdd(&cnt[dst0[i]], 1);
    else if (i < NE0 + NE1)      atomicAdd(&cnt[NOUT0 + dst1[i - NE0]], 1);
    else if (i < CSR_N)          atomicAdd(&cnt[NOUT0 + NOUT1 + dst2[i - NE0 - NE1]], 1);
}

// ---------------------------------------------------------------------------
// scan counts -> offs + cursor. 3 blocks (one per layer).
__global__ __launch_bounds__(1024) void scan_offs(
    const int* __restrict__ cnt, int* __restrict__ offs, int* __restrict__ cursor)
{
    const int L = blockIdx.x;
    const int t = threadIdx.x;
    const int n  = (L == 0) ? NOUT0 : (L == 1) ? NOUT1 : NOUT2;
    const int cb = (L == 0) ? 0 : (L == 1) ? NOUT0 : NOUT0 + NOUT1;
    const int ob = (L == 0) ? 0 : (L == 1) ? NOUT0 + 1 : NOUT0 + NOUT1 + 2;
    const int* c = cnt + cb;
    int* ofs = offs + ob;
    int* cur = cursor + cb;

    __shared__ int sc[1024];
    constexpr int CH = 5;                 // 1024*5 = 5120 >= 5000
    const int base = t * CH;
    int vals[CH];
    int local = 0;
#pragma unroll
    for (int k = 0; k < CH; ++k) {
        const int i = base + k;
        const int v = (i < n) ? c[i] : 0;
        vals[k] = v; local += v;
    }
    sc[t] = local;
    __syncthreads();
    for (int d = 1; d < 1024; d <<= 1) {
        const int v = (t >= d) ? sc[t - d] : 0;
        __syncthreads();
        sc[t] += v;
        __syncthreads();
    }
    int excl = sc[t] - local;
#pragma unroll
    for (int k = 0; k < CH; ++k) {
        const int i = base + k;
        if (i < n) { ofs[i] = excl; cur[i] = excl; }
        excl += vals[k];
    }
    if (t == 1023) ofs[n] = sc[1023];
}

// ---------------------------------------------------------------------------
// transpose+scale (blocks < NTILE) || edge scatter (the rest).
// Store side uint4 (8 halves / 16B per lane) — half the store instructions.
__global__ __launch_bounds__(256) void transpose_scatter(
    const float* __restrict__ data, const float* __restrict__ p0,
    __half* __restrict__ dataT,
    const int* __restrict__ src0, const int* __restrict__ dst0,
    const int* __restrict__ src1, const int* __restrict__ dst1,
    const int* __restrict__ src2, const int* __restrict__ dst2,
    int* __restrict__ cursor, int* __restrict__ csr)
{
    const int t = threadIdx.x;
    const int bid = blockIdx.x;
    if (bid < NTILE) {
        __shared__ float tile[64][65];
        const int c0 = (bid % NTILE_F) * 64;   // F0 dim
        const int r0 = (bid / NTILE_F) * 64;   // B dim
        const int f4 = t & 15, rr = t >> 4;
        const int col = c0 + f4 * 4;
        if (col < F0) {                        // F0 % 4 == 0: exact guard
#pragma unroll
            for (int p = 0; p < 4; ++p) {
                const int br = rr + p * 16;
                const float4 v = *(const float4*)&data[(size_t)(r0 + br) * F0 + col];
                tile[br][f4 * 4 + 0] = v.x; tile[br][f4 * 4 + 1] = v.y;
                tile[br][f4 * 4 + 2] = v.z; tile[br][f4 * 4 + 3] = v.w;
            }
        }
        __syncthreads();
        const int b8 = t & 7, fr = t >> 3;     // fr 0..31; b8: 8 col-groups of 8
#pragma unroll
        for (int p = 0; p < 2; ++p) {
            const int f = c0 + fr + p * 32;
            if (f < F0) {
                const float s = p0[f];
                H8 o;
#pragma unroll
                for (int k = 0; k < 4; ++k)
                    o.h[k] = __floats2half2_rn(tile[b8 * 8 + 2 * k + 0][fr + p * 32] * s,
                                               tile[b8 * 8 + 2 * k + 1][fr + p * 32] * s);
                *(uint4*)&dataT[(size_t)f * Bsz + r0 + b8 * 8] = o.u4;
            }
        }
    } else {
        const int i = (bid - NTILE) * 256 + t;
        if (i < NE0) {
            const int pos = atomicAdd(&cursor[dst0[i]], 1);
            csr[pos] = src0[i];
        } else if (i < NE0 + NE1) {
            const int k = i - NE0;
            const int pos = atomicAdd(&cursor[NOUT0 + dst1[k]], 1);
            csr[NE0 + pos] = src1[k];
        } else if (i < CSR_N) {
            const int k = i - NE0 - NE1;
            const int pos = atomicAdd(&cursor[NOUT0 + NOUT1 + dst2[k]], 1);
            csr[NE0 + NE1 + pos] = src2[k];
        }
    }
}

// ---------------------------------------------------------------------------
// Gather layers (round-12 proven form): block = (dst j, slice s), 64 threads;
// slice = bid & 7; thread t owns cols [slice*128 + 2t, +2) as half2.
template<int LAYER>
__global__ __launch_bounds__(64) void layer_slice(
    const __half* __restrict__ xT, const int* __restrict__ csr,
    const int* __restrict__ offs, const float* __restrict__ pnext,
    __half* __restrict__ yT)
{
    __shared__ int sidx[MAXIDX];
    const int bid = blockIdx.x;
    const int slice = bid & (NSLICE - 1);
    const int j = bid >> 3;
    const int t = threadIdx.x;
    const int beg = offs[j], end = offs[j + 1];
    const int n = end - beg;
    const int np = n < MAXIDX ? n : MAXIDX;
    for (int i = t; i < np; i += 64) sidx[i] = csr[beg + i];
    __syncthreads();

    const int c = slice * SLW + t * 2;
    float a0x = 0.f, a0y = 0.f, a1x = 0.f, a1y = 0.f;
    float a2x = 0.f, a2y = 0.f, a3x = 0.f, a3y = 0.f;
    int e = 0;
    for (; e + 4 <= np; e += 4) {
        const __half2 v0 = *(const __half2*)&xT[(size_t)sidx[e + 0] * Bsz + c];
        const __half2 v1 = *(const __half2*)&xT[(size_t)sidx[e + 1] * Bsz + c];
        const __half2 v2 = *(const __half2*)&xT[(size_t)sidx[e + 2] * Bsz + c];
        const __half2 v3 = *(const __half2*)&xT[(size_t)sidx[e + 3] * Bsz + c];
        const float2 f0 = __half22float2(v0);
        const float2 f1 = __half22float2(v1);
        const float2 f2 = __half22float2(v2);
        const float2 f3 = __half22float2(v3);
        a0x += f0.x; a0y += f0.y; a1x += f1.x; a1y += f1.y;
        a2x += f2.x; a2y += f2.y; a3x += f3.x; a3y += f3.y;
    }
    for (; e < np; ++e) {
        const float2 f = __half22float2(*(const __half2*)&xT[(size_t)sidx[e] * Bsz + c]);
        a0x += f.x; a0y += f.y;
    }
    for (int ee = MAXIDX; ee < n; ++ee) {   // overflow fallback (never in practice)
        const float2 f = __half22float2(*(const __half2*)&xT[(size_t)csr[beg + ee] * Bsz + c]);
        a0x += f.x; a0y += f.y;
    }
    const float ax = a0x + a1x + a2x + a3x;
    const float ay = a0y + a1y + a2y + a3y;

    const float inv = 1.0f / fmaxf((float)n, 1.0f);
    const float sc = (pnext ? pnext[j] : 1.0f) * inv;
    const __half2 o = __floats2half2_rn(fmaxf(ax, 0.f) * sc, fmaxf(ay, 0.f) * sc);
    *(__half2*)&yT[(size_t)j * Bsz + c] = o;
}

// ---------------------------------------------------------------------------
// head GEMM. out (B,10) = y2 (B,256) @ W.T + b, y2 transposed fp16.
__global__ __launch_bounds__(256) void head_gemm(
    const __half* __restrict__ y2T, const float* __restrict__ W,
    const float* __restrict__ bias, float* __restrict__ out)
{
    __shared__ float ws[10 * 256];
    __shared__ float bs[10];
    const int t = threadIdx.x;
    for (int i = t; i < 10 * 256; i += 256) ws[i] = W[i];
    if (t < 10) bs[t] = bias[t];
    __syncthreads();

    const int b = blockIdx.x * 256 + t;
    float acc[10];
#pragma unroll
    for (int o = 0; o < 10; ++o) acc[o] = bs[o];
    for (int k = 0; k < 256; ++k) {
        const float v = __half2float(y2T[(size_t)k * Bsz + b]);
#pragma unroll
        for (int o = 0; o < 10; ++o) acc[o] += v * ws[o * 256 + k];
    }
#pragma unroll
    for (int o = 0; o < 10; ++o) out[(size_t)b * 10 + o] = acc[o];
}

// ---------------------------------------------------------------------------
extern "C" void kernel_launch(void* const* d_in, const int* in_sizes, int n_in,
                              void* d_out, int out_size, void* d_ws, size_t ws_size,
                              hipStream_t stream)
{
    const float* data = (const float*)d_in[0];
    const float* p0   = (const float*)d_in[1];
    const float* p1   = (const float*)d_in[2];
    const float* p2   = (const float*)d_in[3];
    const float* W    = (const float*)d_in[4];
    const float* bias = (const float*)d_in[5];
    const int* src0 = (const int*)d_in[6];
    const int* dst0 = (const int*)d_in[7];
    const int* src1 = (const int*)d_in[8];
    const int* dst1 = (const int*)d_in[9];
    const int* src2 = (const int*)d_in[10];
    const int* dst2 = (const int*)d_in[11];

    char* ws = (char*)d_ws;
    auto align = [](size_t x) { return (x + 255) & ~size_t(255); };
    size_t o = 0;
    __half* dataT = (__half*)(ws + o); o = align(o + (size_t)F0 * Bsz * 2);
    __half* y0    = (__half*)(ws + o); o = align(o + (size_t)NOUT0 * Bsz * 2);
    __half* y1    = (__half*)(ws + o); o = align(o + (size_t)NOUT1 * Bsz * 2);
    __half* y2    = (__half*)(ws + o); o = align(o + (size_t)NOUT2 * Bsz * 2);
    int* cnt      = (int*)(ws + o);    o = align(o + (size_t)CNT_N * 4);
    int* offs     = (int*)(ws + o);    o = align(o + (size_t)OFFS_N * 4);
    int* cursor   = (int*)(ws + o);    o = align(o + (size_t)CNT_N * 4);
    int* csr      = (int*)(ws + o);    o = align(o + (size_t)CSR_N * 4);

    hipMemsetAsync(cnt, 0, (size_t)CNT_N * 4, stream);
    count_edges<<<SCB, 256, 0, stream>>>(dst0, dst1, dst2, cnt);
    scan_offs<<<3, 1024, 0, stream>>>(cnt, offs, cursor);
    transpose_scatter<<<NTILE + SCB, 256, 0, stream>>>(
        data, p0, dataT, src0, dst0, src1, dst1, src2, dst2, cursor, csr);
    layer_slice<0><<<NOUT0 * NSLICE, 64, 0, stream>>>(dataT, csr, offs, p1, y0);
    layer_slice<1><<<NOUT1 * NSLICE, 64, 0, stream>>>(y0, csr + NE0, offs + NOUT0 + 1, p2, y1);
    layer_slice<2><<<NOUT2 * NSLICE, 64, 0, stream>>>(y1, csr + NE0 + NE1,
                                                      offs + NOUT0 + NOUT1 + 2, nullptr, y2);
    head_gemm<<<Bsz / 256, 256, 0, stream>>>(y2, W, bias, (float*)d_out);
}